// Round 8
// baseline (173.858 us; speedup 1.0000x reference)
//
#include <hip/hip_runtime.h>
#include <hip/hip_bf16.h>

// Problem: B=2, S=2048, E=1024, H=16, D=64, causal MHA, fp32 in/out.
#define B_ 2
#define S_ 2048
#define E_ 1024
#define H_ 16
#define D_ 64
#define QKV_N 3072
// SCALE * log2(e), folded into wq at cast time -> attn uses exp2 directly.
#define C2_ 0.18033688011112042f

typedef __attribute__((ext_vector_type(8))) unsigned short ushort8_t;
typedef __attribute__((ext_vector_type(8))) short short8_t;   // 8 bf16 MFMA frag
typedef __attribute__((ext_vector_type(4))) float f32x4;      // MFMA accum frag

__device__ __forceinline__ unsigned short f2b(float f) {
    union { float f; unsigned u; } x; x.f = f;
    unsigned r = x.u + 0x7FFFu + ((x.u >> 16) & 1u);
    return (unsigned short)(r >> 16);
}
__device__ __forceinline__ ushort2 pkbf(float a, float b) {
    union { __hip_bfloat162 h; ushort2 u; } c;
    c.h = __float22bfloat162_rn(make_float2(a, b));
    return c.u;
}
// async global->LDS, 16 B per lane. LDS base wave-uniform; HW adds lane*16.
__device__ __forceinline__ void glds16(const unsigned short* g, unsigned short* l) {
    __builtin_amdgcn_global_load_lds((const __attribute__((address_space(1))) void*)g,
                                     (__attribute__((address_space(3))) void*)l, 16, 0, 0);
}

// ---------------- fused cast: x + 4 weights, one launch ----------------
__global__ __launch_bounds__(256) void cast_all(const float* __restrict__ x,
                                                const float* __restrict__ wq,
                                                const float* __restrict__ wk,
                                                const float* __restrict__ wv,
                                                const float* __restrict__ wo,
                                                unsigned short* __restrict__ xb,
                                                unsigned short* __restrict__ wb) {
    int idx = blockIdx.x * 256 + threadIdx.x;
    const float* src; unsigned short* dst; float s = 1.f; int j;
    if (idx < 1048576) {
        src = x; dst = xb; j = idx;
    } else {
        j = idx - 1048576;
        int y = j >> 18;                       // block-uniform (aligned boundaries)
        src = (y == 0) ? wq : (y == 1) ? wk : (y == 2) ? wv : wo;
        dst = wb + (size_t)y * 1048576;
        j &= 262143;
        if (y == 0) s = C2_;
    }
    float4 v = ((const float4*)src)[j];
    ushort2 lo = pkbf(v.x * s, v.y * s), hi = pkbf(v.z * s, v.w * s);
    ((ushort4*)dst)[j] = make_ushort4(lo.x, lo.y, hi.x, hi.y);
}

// ---------------- bf16 GEMM, C = A * Bt^T, BK=64 (two 32-K halves/barrier) ----
// Physical LDS layout of each half identical to the verified [TM][32] pattern;
// half 1 lives at offset TM*32 (Bs: 128*32). 32 MFMA per barrier pair (TM=128).
// m0/n0 passed in so wrappers can apply XCD-aware block swizzles.
// VT: blocks with n0 >= 2048 (the V third of fused QKV) write their output
// TRANSPOSED in place: Vt[r = col-2048][s = row] -> C[b*2048 + 2r + (s>>10)]
// [2048 + (s&1023)] (injective over the V-third cells; each cell written once).
// attn reads V with the matching addressing, so transpose_v is deleted.
template <int TM, bool OUT_BF16, bool VT>
__device__ __forceinline__ void gemm_bt_body(const unsigned short* __restrict__ A,
                                             const unsigned short* __restrict__ Bt,
                                             void* __restrict__ Cout,
                                             int m0, int n0, int N, int K) {
    __shared__ unsigned short As[2 * TM * 32];
    __shared__ unsigned short Bs[2 * 128 * 32];
    const int tid = threadIdx.x;
    const int wave = tid >> 6;
    const int lane = tid & 63;
    const int wm = (wave >> 1) * (TM / 2);
    const int wn = (wave & 1) * 64;
    const int quad = lane >> 4;
    const int l15 = lane & 15;
    constexpr int MI = TM / 32;

    f32x4 acc[MI][4] = {};

    const int srow = lane >> 2;
    const int scb  = (lane & 3) * 8;
    const unsigned short* gB0 = Bt + (size_t)(n0 + wave * 32 + srow) * K + scb;
    const unsigned short* gB1 = gB0 + (size_t)16 * K;
    unsigned short* lB0 = Bs + wave * 1024;
    unsigned short* lB1 = lB0 + 512;
    const unsigned short* gA0;
    const unsigned short* gA1 = nullptr;
    unsigned short* lA0;
    unsigned short* lA1 = nullptr;
    if (TM == 128) {
        gA0 = A + (size_t)(m0 + wave * 32 + srow) * K + scb;
        gA1 = gA0 + (size_t)16 * K;
        lA0 = As + wave * 1024; lA1 = lA0 + 512;
    } else {
        gA0 = A + (size_t)(m0 + wave * 16 + srow) * K + scb;
        lA0 = As + wave * 512;
    }

    for (int k0 = 0; k0 < K; k0 += 64) {
        __syncthreads();
        // half 0 (k0) and half 1 (k0+32); half-1 LDS region at +TM*32 / +128*32
        glds16(gA0 + k0, lA0);
        glds16(gA0 + k0 + 32, lA0 + TM * 32);
        if (TM == 128) {
            glds16(gA1 + k0, lA1);
            glds16(gA1 + k0 + 32, lA1 + TM * 32);
        }
        glds16(gB0 + k0, lB0);
        glds16(gB0 + k0 + 32, lB0 + 128 * 32);
        glds16(gB1 + k0, lB1);
        glds16(gB1 + k0 + 32, lB1 + 128 * 32);
        __syncthreads();

#pragma unroll
        for (int h = 0; h < 2; ++h) {
            const unsigned short* ah = As + h * TM * 32;
            const unsigned short* bh = Bs + h * 128 * 32;
            short8_t af[MI], bfv[4];
#pragma unroll
            for (int mi = 0; mi < MI; ++mi)
                af[mi] = *(const short8_t*)(&ah[(wm + mi * 16 + l15) * 32 + quad * 8]);
#pragma unroll
            for (int ni = 0; ni < 4; ++ni)
                bfv[ni] = *(const short8_t*)(&bh[(wn + ni * 16 + l15) * 32 + quad * 8]);
#pragma unroll
            for (int mi = 0; mi < MI; ++mi)
#pragma unroll
                for (int ni = 0; ni < 4; ++ni)
                    acc[mi][ni] = __builtin_amdgcn_mfma_f32_16x16x32_bf16(
                        af[mi], bfv[ni], acc[mi][ni], 0, 0, 0);
        }
    }

    if (VT && n0 >= 2048) {
        // transposed in-place V write: 16 x 8B stores per thread
#pragma unroll
        for (int mi = 0; mi < MI; ++mi)
#pragma unroll
            for (int ni = 0; ni < 4; ++ni) {
                int col = n0 + wn + ni * 16 + l15;       // 2048..3071
                int r0  = m0 + wm + mi * 16 + quad * 4;  // s index, 4-aligned
                int bb  = r0 >> 11, s = r0 & 2047;
                size_t drow = (size_t)bb * 2048 + 2 * (col - 2048) + (s >> 10);
                unsigned short* dp = (unsigned short*)Cout + drow * QKV_N + 2048 + (s & 1023);
                *(ushort4*)dp = make_ushort4(f2b(acc[mi][ni][0]), f2b(acc[mi][ni][1]),
                                             f2b(acc[mi][ni][2]), f2b(acc[mi][ni][3]));
            }
        return;
    }

#pragma unroll
    for (int mi = 0; mi < MI; ++mi)
#pragma unroll
        for (int ni = 0; ni < 4; ++ni)
#pragma unroll
            for (int r = 0; r < 4; ++r) {
                int row = m0 + wm + mi * 16 + quad * 4 + r;
                int col = n0 + wn + ni * 16 + l15;
                float val = acc[mi][ni][r];
                if (OUT_BF16)
                    ((unsigned short*)Cout)[(size_t)row * N + col] = f2b(val);
                else
                    ((float*)Cout)[(size_t)row * N + col] = val;
            }
}

// Fused QKV: [4096,1024] x [3072,1024]^T -> [4096,3072] bf16.  768 blocks;
// (256,3) -> 3 blocks/CU so the whole grid co-resides.
// XCD-chunked bijective swizzle (768 % 8 == 0): each XCD gets a contiguous
// 96-block chunk -> contiguous m-range per XCD-L2 -> better A-panel reuse.
// V third written transposed in place (see gemm_bt_body).
__global__ __launch_bounds__(256, 3) void gemm_qkv(const unsigned short* __restrict__ xb,
                                                   const unsigned short* __restrict__ wqkv,
                                                   unsigned short* __restrict__ qkv) {
    int id = blockIdx.x + 24 * blockIdx.y;       // 0..767
    int sw = (id & 7) * 96 + (id >> 3);          // bijective, 96 blocks/XCD
    int n0 = (sw % 24) * 128;
    int m0 = (sw / 24) * 128;
    gemm_bt_body<128, true, true>(xb, wqkv, qkv, m0, n0, QKV_N, E_);
}

// Out-proj: TM=64, 512 blocks -> 2/CU.  Same XCD-chunked bijective swizzle
// (512 % 8 == 0): each XCD gets 64 consecutive sw ids = an m-contiguous
// 512-row span x all n -> A-panel 1MB + B 2MB fits the 4MB per-XCD L2.
__global__ __launch_bounds__(256, 2) void gemm_out(const unsigned short* __restrict__ a,
                                                   const unsigned short* __restrict__ wob,
                                                   float* __restrict__ c) {
    int id = blockIdx.x + 8 * blockIdx.y;        // 0..511
    int sw = (id & 7) * 64 + (id >> 3);          // bijective, 64 blocks/XCD
    gemm_bt_body<64, false, false>(a, wob, c, (sw >> 3) * 64, (sw & 7) * 128, E_, E_);
}

// ---------------- MFMA causal flash attention v17 ----------------
// LDS-traffic halving.  v14-v16 rocprof invariance (time ~43us while FETCH,
// wave activity, and staging schedule all changed) + arithmetic (per CU-iter
// 2 blk x 8 waves x ~18KB ds_read = 288KB @ 85-128 B/cy = ~2250-3400cy ~=
// measured 2100cy/iter) shows the kernel sits at its LDS-read floor for the
// 16-rows-per-wave decomposition.  Fix: each wave now owns 32 q rows as TWO
// 16-row output fragments (A: Q0..+15, B: Q0+16..+31) that SHARE every K and
// V ds_read -- ak/bv reads feed 2 MFMAs instead of 1, halving K/V LDS traffic
// (P round-trip unchanged).  Block = 256 threads (4 waves x 32 rows = one
// 128-row chunk), grid still 512 = 2 blocks/CU; LDS 64KB/block (ring 48 +
// Ps 16) -> 2/CU.  Balance remap + ring-3 counted-vmcnt DMA staging kept
// (staging now 4 glds16/tile, 256thr x 16B = 32 rows each -> vmcnt(4)).
// Occupancy counter WILL read ~half (8 waves/CU) -- expected, not regression.
__global__ __launch_bounds__(256, 2) void attn_kernel(const unsigned short* __restrict__ QKV,
                                                      unsigned short* __restrict__ O) {
    __shared__ unsigned short Ks[3][64 * 64];    // [ring][kv][d]  swizzled
    __shared__ unsigned short Vs[3][64 * 64];    // [ring][d][kv]  swizzled
    __shared__ unsigned short Ps[4][2][16 * 64]; // per wave x frag [q][kv] swizzled

    const int b = blockIdx.z, h = blockIdx.y;
    const int cx = blockIdx.x;
    const int c0 = (cx & 1) ? (15 - (cx >> 1)) : (cx >> 1);
    const int j = (b == 0) ? c0 : (15 - c0);    // chunk id 0..15, balance-remapped
    const int tid = threadIdx.x;
    const int w = tid >> 6, lane = tid & 63;
    const int quad = lane >> 4, l15 = lane & 15;
    const int lx = l15 & 7;
    const int Q0 = j * 128 + w * 32;            // frag A rows Q0..+15, frag B +16..+31

    // Q B-frags for both 16-row fragments (pre-scaled by C2_ via wq)
    const size_t qoA = (size_t)(b * S_ + Q0 + l15) * QKV_N + h * D_;
    const size_t qoB = qoA + (size_t)16 * QKV_N;
    short8_t bqA0 = *(const short8_t*)(QKV + qoA + quad * 8);
    short8_t bqA1 = *(const short8_t*)(QKV + qoA + 32 + quad * 8);
    short8_t bqB0 = *(const short8_t*)(QKV + qoB + quad * 8);
    short8_t bqB1 = *(const short8_t*)(QKV + qoB + 32 + quad * 8);

    f32x4 OaccA[4] = {}, OaccB[4] = {};
    f32x4 LaccA = {}, LaccB = {};
    const int qgA = Q0 + l15, qgB = Q0 + 16 + l15;
    short8_t ones;
#pragma unroll
    for (int i = 0; i < 8; ++i) ones[i] = (short)0x3F80;   // bf16 1.0

    const int fo0 = ((quad) ^ lx) * 8;
    const int fo1 = ((4 + quad) ^ lx) * 8;
    const int krow = l15 * 64;
    int pwo[4];
#pragma unroll
    for (int tm = 0; tm < 4; ++tm)
        pwo[tm] = ((tm * 2 + (quad >> 1)) ^ lx) * 8 + (quad & 1) * 4;

    // DMA staging: 256 threads x 16B = 32 rows per glds16; a 64x64 tile takes
    // two calls (rows 0-31, 32-63).  LDS dest linear (wave-uniform base +
    // lane*16); swizzle lives in the SOURCE column (rows r and r+32 share
    // (r&7) so scw is reusable for the upper half).
    const int srow = tid >> 3;                  // 0..31
    const int scb  = tid & 7;
    const int scw  = (scb ^ (srow & 7)) * 8;    // inverse-swizzled source col
    const int wofs = w * 512;                   // wave-uniform LDS base (shorts)
    const unsigned short* KsrcB  = QKV + (size_t)(b * S_ + srow) * QKV_N + 1024 + h * D_ + scw;
    const unsigned short* KsrcB2 = KsrcB + (size_t)32 * QKV_N;
    // V third of qkv, transposed in place: row' = b*2048 + 2*(h*64+d) + (s>>10),
    // col' = 2048 + (s&1023).  This thread stages d = srow (and d = srow+32).
    const unsigned short* VsrcB  = QKV + (size_t)(b * S_ + 2 * (h * D_ + srow)) * QKV_N + 2048 + scw;
    const unsigned short* VsrcB2 = VsrcB + (size_t)64 * QKV_N;   // d+32 -> +64 rows

    auto issue = [&](int bn, int ktn) {
        size_t vo = (size_t)(ktn >> 10) * QKV_N + (ktn & 1023);
        glds16(KsrcB  + (size_t)ktn * QKV_N, &Ks[bn][wofs]);
        glds16(KsrcB2 + (size_t)ktn * QKV_N, &Ks[bn][wofs + 2048]);
        glds16(VsrcB  + vo, &Vs[bn][wofs]);
        glds16(VsrcB2 + vo, &Vs[bn][wofs + 2048]);
    };

    const int ntiles = 2 * j + 2;               // 64-kv tiles this chunk needs (>=2)
    issue(0, 0);                                // prologue: depth-2 prefetch
    issue(1, 64);
    int bi = 0;

    for (int t = 0; t < ntiles; ++t) {
        const int kt = t * 64;
        // counted wait: tile t's 4 loads (oldest outstanding) complete;
        // tile t+1's 4 stay in flight across the barrier.
        if (t + 1 < ntiles) asm volatile("s_waitcnt vmcnt(4)" ::: "memory");
        else                asm volatile("s_waitcnt vmcnt(0)" ::: "memory");
        __builtin_amdgcn_s_barrier();
        __builtin_amdgcn_sched_barrier(0);      // no LDS reads hoist above barrier
        if (t + 2 < ntiles) {
            int b2 = bi + 2; if (b2 >= 3) b2 -= 3;
            issue(b2, kt + 128);
        }

        if (kt <= Q0 + 31) {                    // tile inside this wave's 32 rows
            const bool h2 = (kt + 32 <= Q0 + 31);   // kv half 1 needed (frag B)

            if (kt + 63 <= Q0) {
                // ---- full tile for BOTH frags: shared ak reads, 4 MFMA each ----
#pragma unroll
                for (int tm = 0; tm < 4; ++tm) {
                    short8_t ak0 = *(const short8_t*)(&Ks[bi][tm * 1024 + krow + fo0]);
                    short8_t ak1 = *(const short8_t*)(&Ks[bi][tm * 1024 + krow + fo1]);
                    f32x4 stA = {0.f, 0.f, 0.f, 0.f}, stB = {0.f, 0.f, 0.f, 0.f};
                    __builtin_amdgcn_s_setprio(1);
                    stA = __builtin_amdgcn_mfma_f32_16x16x32_bf16(ak0, bqA0, stA, 0, 0, 0);
                    stA = __builtin_amdgcn_mfma_f32_16x16x32_bf16(ak1, bqA1, stA, 0, 0, 0);
                    stB = __builtin_amdgcn_mfma_f32_16x16x32_bf16(ak0, bqB0, stB, 0, 0, 0);
                    stB = __builtin_amdgcn_mfma_f32_16x16x32_bf16(ak1, bqB1, stB, 0, 0, 0);
                    __builtin_amdgcn_s_setprio(0);
                    float a0 = __builtin_amdgcn_exp2f(stA[0]);
                    float a1 = __builtin_amdgcn_exp2f(stA[1]);
                    float a2 = __builtin_amdgcn_exp2f(stA[2]);
                    float a3 = __builtin_amdgcn_exp2f(stA[3]);
                    float b0 = __builtin_amdgcn_exp2f(stB[0]);
                    float b1 = __builtin_amdgcn_exp2f(stB[1]);
                    float b2f = __builtin_amdgcn_exp2f(stB[2]);
                    float b3 = __builtin_amdgcn_exp2f(stB[3]);
                    ushort2 pa = pkbf(a0, a1), pc = pkbf(a2, a3);
                    ushort2 qa = pkbf(b0, b1), qc = pkbf(b2f, b3);
                    *(ushort4*)(&Ps[w][0][krow + pwo[tm]]) = make_ushort4(pa.x, pa.y, pc.x, pc.y);
                    *(ushort4*)(&Ps[w][1][krow + pwo[tm]]) = make_ushort4(qa.x, qa.y, qc.x, qc.y);
                }
            } else {
                // ---- diagonal area: per-frag masking; zero dead PsA blocks ----
                const int need = h2 ? 4 : 2;    // tm range frag B touches
                for (int tm = 0; tm < need; ++tm) {
                    short8_t ak0 = *(const short8_t*)(&Ks[bi][tm * 1024 + krow + fo0]);
                    short8_t ak1 = *(const short8_t*)(&Ks[bi][tm * 1024 + krow + fo1]);
                    const int kvb = kt + tm * 16 + quad * 4;
                    // frag B: always active for tm < need
                    {
                        f32x4 st = {0.f, 0.f, 0.f, 0.f};
                        __builtin_amdgcn_s_setprio(1);
                        st = __builtin_amdgcn_mfma_f32_16x16x32_bf16(ak0, bqB0, st, 0, 0, 0);
                        st = __builtin_amdgcn_mfma_f32_16x16x32_bf16(ak1, bqB1, st, 0, 0, 0);
                        __builtin_amdgcn_s_setprio(0);
                        float p0 = (kvb     > qgB) ? 0.f : __builtin_amdgcn_exp2f(st[0]);
                        float p1 = (kvb + 1 > qgB) ? 0.f : __builtin_amdgcn_exp2f(st[1]);
                        float p2 = (kvb + 2 > qgB) ? 0.f : __builtin_amdgcn_exp2f(st[2]);
                        float p3 = (kvb + 3 > qgB) ? 0.f : __builtin_amdgcn_exp2f(st[3]);
                        ushort2 a = pkbf(p0, p1), c2 = pkbf(p2, p3);
                        *(ushort4*)(&Ps[w][1][krow + pwo[tm]]) = make_ushort4(a.x, a.y, c2.x, c2.y);
                    }
                    // frag A: active only while tm overlaps its 16 rows
                    if (kt + tm * 16 <= Q0 + 15) {
                        f32x4 st = {0.f, 0.f, 0.f, 0.f};
                        __builtin_amdgcn_s_setprio(1);
                        st = __builtin_amdgcn_mfma_f32_16x16x32_bf16(ak0, bqA0, st, 0, 0, 0);
                        st = __builtin_amdgcn_mfma_f32_16x16x32_bf16(ak1, bqA1, st, 0, 0, 0);
                        __builtin_amdgcn_s_setprio(0);
                        float p0 = (kvb     > qgA) ? 0.f : __builtin_amdgcn_exp2f(st[0]);
                        float p1 = (kvb + 1 > qgA) ? 0.f : __builtin_amdgcn_exp2f(st[1]);
                        float p2 = (kvb + 2 > qgA) ? 0.f : __builtin_amdgcn_exp2f(st[2]);
                        float p3 = (kvb + 3 > qgA) ? 0.f : __builtin_amdgcn_exp2f(st[3]);
                        ushort2 a = pkbf(p0, p1), c2 = pkbf(p2, p3);
                        *(ushort4*)(&Ps[w][0][krow + pwo[tm]]) = make_ushort4(a.x, a.y, c2.x, c2.y);
                    } else {
                        *(ushort4*)(&Ps[w][0][krow + pwo[tm]]) = make_ushort4(0, 0, 0, 0);
                    }
                }
            }

            // ---- O += P V for both frags; Lacc += P * ones (row-sums) ----
            // bv reads shared: 4 ds_read feed 10 MFMAs (5 per frag).
#pragma unroll
            for (int kh = 0; kh < 2; ++kh) {
                if (kh == 1 && !h2) break;
                const int fo = kh ? fo1 : fo0;
                short8_t bv[4];
#pragma unroll
                for (int tn = 0; tn < 4; ++tn)
                    bv[tn] = *(const short8_t*)(&Vs[bi][tn * 1024 + krow + fo]);
                short8_t apA = *(const short8_t*)(&Ps[w][0][krow + fo]);
                short8_t apB = *(const short8_t*)(&Ps[w][1][krow + fo]);
                __builtin_amdgcn_s_setprio(1);
#pragma unroll
                for (int tn = 0; tn < 4; ++tn)
                    OaccA[tn] = __builtin_amdgcn_mfma_f32_16x16x32_bf16(
                        apA, bv[tn], OaccA[tn], 0, 0, 0);
                LaccA = __builtin_amdgcn_mfma_f32_16x16x32_bf16(apA, ones, LaccA, 0, 0, 0);
#pragma unroll
                for (int tn = 0; tn < 4; ++tn)
                    OaccB[tn] = __builtin_amdgcn_mfma_f32_16x16x32_bf16(
                        apB, bv[tn], OaccB[tn], 0, 0, 0);
                LaccB = __builtin_amdgcn_mfma_f32_16x16x32_bf16(apB, ones, LaccB, 0, 0, 0);
                __builtin_amdgcn_s_setprio(0);
            }
        }

        bi = (bi + 1 == 3) ? 0 : bi + 1;
    }

    // ---- epilogue: normalize, store bf16 (both frags).  Lacc[r] = rowsum of
    // q = (frag base)+quad*4+r, uniform across l15 -- matches Oacc rows.
    float lirA[4], lirB[4];
#pragma unroll
    for (int r = 0; r < 4; ++r) {
        lirA[r] = 1.f / LaccA[r];
        lirB[r] = 1.f / LaccB[r];
    }
#pragma unroll
    for (int tn = 0; tn < 4; ++tn)
#pragma unroll
        for (int r = 0; r < 4; ++r) {
            int rowA = Q0 + quad * 4 + r;
            O[(size_t)(b * S_ + rowA) * E_ + h * D_ + tn * 16 + l15] =
                f2b(OaccA[tn][r] * lirA[r]);
            int rowB = Q0 + 16 + quad * 4 + r;
            O[(size_t)(b * S_ + rowB) * E_ + h * D_ + tn * 16 + l15] =
                f2b(OaccB[tn][r] * lirB[r]);
        }
}

// ---------------- launch ----------------
extern "C" void kernel_launch(void* const* d_in, const int* in_sizes, int n_in,
                              void* d_out, int out_size, void* d_ws, size_t ws_size,
                              hipStream_t stream) {
    const float* x  = (const float*)d_in[0];
    const float* wq = (const float*)d_in[1];
    const float* wk = (const float*)d_in[2];
    const float* wv = (const float*)d_in[3];
    const float* wo = (const float*)d_in[4];
    float* out = (float*)d_out;

    unsigned short* ws   = (unsigned short*)d_ws;
    unsigned short* xb   = ws;                   // [0, 4194304)
    unsigned short* wqkv = ws + 4194304;         // 3 x 1048576 (wq|wk|wv)
    unsigned short* wob  = ws + 7340032;         // 1048576
    unsigned short* qkvb = ws + 8388608;         // 4096 x 3072 = 12582912
    unsigned short* ab   = ws + 20971520;        // 4194304

    cast_all<<<8192, 256, 0, stream>>>(x, wq, wk, wv, wo, xb, wqkv);
    gemm_qkv<<<dim3(24, 32), 256, 0, stream>>>(xb, wqkv, qkvb);
    attn_kernel<<<dim3(16, 16, 2), 256, 0, stream>>>(qkvb, ab);
    gemm_out<<<dim3(8, 64), 256, 0, stream>>>(ab, wob, out);
}

// Round 9
// 161.992 us; speedup vs baseline: 1.0733x; 1.0733x over previous
//
#include <hip/hip_runtime.h>
#include <hip/hip_bf16.h>

// Problem: B=2, S=2048, E=1024, H=16, D=64, causal MHA, fp32 in/out.
#define B_ 2
#define S_ 2048
#define E_ 1024
#define H_ 16
#define D_ 64
#define QKV_N 3072
// SCALE * log2(e), folded into wq at cast time -> attn uses exp2 directly.
#define C2_ 0.18033688011112042f

typedef __attribute__((ext_vector_type(8))) unsigned short ushort8_t;
typedef __attribute__((ext_vector_type(8))) short short8_t;   // 8 bf16 MFMA frag
typedef __attribute__((ext_vector_type(4))) float f32x4;      // MFMA accum frag

__device__ __forceinline__ unsigned short f2b(float f) {
    union { float f; unsigned u; } x; x.f = f;
    unsigned r = x.u + 0x7FFFu + ((x.u >> 16) & 1u);
    return (unsigned short)(r >> 16);
}
__device__ __forceinline__ ushort2 pkbf(float a, float b) {
    union { __hip_bfloat162 h; ushort2 u; } c;
    c.h = __float22bfloat162_rn(make_float2(a, b));
    return c.u;
}
// async global->LDS, 16 B per lane. LDS base wave-uniform; HW adds lane*16.
__device__ __forceinline__ void glds16(const unsigned short* g, unsigned short* l) {
    __builtin_amdgcn_global_load_lds((const __attribute__((address_space(1))) void*)g,
                                     (__attribute__((address_space(3))) void*)l, 16, 0, 0);
}

// ---------------- fused cast: x + 4 weights, one launch ----------------
__global__ __launch_bounds__(256) void cast_all(const float* __restrict__ x,
                                                const float* __restrict__ wq,
                                                const float* __restrict__ wk,
                                                const float* __restrict__ wv,
                                                const float* __restrict__ wo,
                                                unsigned short* __restrict__ xb,
                                                unsigned short* __restrict__ wb) {
    int idx = blockIdx.x * 256 + threadIdx.x;
    const float* src; unsigned short* dst; float s = 1.f; int j;
    if (idx < 1048576) {
        src = x; dst = xb; j = idx;
    } else {
        j = idx - 1048576;
        int y = j >> 18;                       // block-uniform (aligned boundaries)
        src = (y == 0) ? wq : (y == 1) ? wk : (y == 2) ? wv : wo;
        dst = wb + (size_t)y * 1048576;
        j &= 262143;
        if (y == 0) s = C2_;
    }
    float4 v = ((const float4*)src)[j];
    ushort2 lo = pkbf(v.x * s, v.y * s), hi = pkbf(v.z * s, v.w * s);
    ((ushort4*)dst)[j] = make_ushort4(lo.x, lo.y, hi.x, hi.y);
}

// ---------------- bf16 GEMM, C = A * Bt^T, BK=64 (two 32-K halves/barrier) ----
// Physical LDS layout of each half identical to the verified [TM][32] pattern;
// half 1 lives at offset TM*32 (Bs: 128*32). 32 MFMA per barrier pair (TM=128).
// m0/n0 passed in so wrappers can apply XCD-aware block swizzles.
// VT: blocks with n0 >= 2048 (the V third of fused QKV) write their output
// TRANSPOSED in place: Vt[r = col-2048][s = row] -> C[b*2048 + 2r + (s>>10)]
// [2048 + (s&1023)] (injective over the V-third cells; each cell written once).
// attn reads V with the matching addressing, so transpose_v is deleted.
template <int TM, bool OUT_BF16, bool VT>
__device__ __forceinline__ void gemm_bt_body(const unsigned short* __restrict__ A,
                                             const unsigned short* __restrict__ Bt,
                                             void* __restrict__ Cout,
                                             int m0, int n0, int N, int K) {
    __shared__ unsigned short As[2 * TM * 32];
    __shared__ unsigned short Bs[2 * 128 * 32];
    const int tid = threadIdx.x;
    const int wave = tid >> 6;
    const int lane = tid & 63;
    const int wm = (wave >> 1) * (TM / 2);
    const int wn = (wave & 1) * 64;
    const int quad = lane >> 4;
    const int l15 = lane & 15;
    constexpr int MI = TM / 32;

    f32x4 acc[MI][4] = {};

    const int srow = lane >> 2;
    const int scb  = (lane & 3) * 8;
    const unsigned short* gB0 = Bt + (size_t)(n0 + wave * 32 + srow) * K + scb;
    const unsigned short* gB1 = gB0 + (size_t)16 * K;
    unsigned short* lB0 = Bs + wave * 1024;
    unsigned short* lB1 = lB0 + 512;
    const unsigned short* gA0;
    const unsigned short* gA1 = nullptr;
    unsigned short* lA0;
    unsigned short* lA1 = nullptr;
    if (TM == 128) {
        gA0 = A + (size_t)(m0 + wave * 32 + srow) * K + scb;
        gA1 = gA0 + (size_t)16 * K;
        lA0 = As + wave * 1024; lA1 = lA0 + 512;
    } else {
        gA0 = A + (size_t)(m0 + wave * 16 + srow) * K + scb;
        lA0 = As + wave * 512;
    }

    for (int k0 = 0; k0 < K; k0 += 64) {
        __syncthreads();
        // half 0 (k0) and half 1 (k0+32); half-1 LDS region at +TM*32 / +128*32
        glds16(gA0 + k0, lA0);
        glds16(gA0 + k0 + 32, lA0 + TM * 32);
        if (TM == 128) {
            glds16(gA1 + k0, lA1);
            glds16(gA1 + k0 + 32, lA1 + TM * 32);
        }
        glds16(gB0 + k0, lB0);
        glds16(gB0 + k0 + 32, lB0 + 128 * 32);
        glds16(gB1 + k0, lB1);
        glds16(gB1 + k0 + 32, lB1 + 128 * 32);
        __syncthreads();

#pragma unroll
        for (int h = 0; h < 2; ++h) {
            const unsigned short* ah = As + h * TM * 32;
            const unsigned short* bh = Bs + h * 128 * 32;
            short8_t af[MI], bfv[4];
#pragma unroll
            for (int mi = 0; mi < MI; ++mi)
                af[mi] = *(const short8_t*)(&ah[(wm + mi * 16 + l15) * 32 + quad * 8]);
#pragma unroll
            for (int ni = 0; ni < 4; ++ni)
                bfv[ni] = *(const short8_t*)(&bh[(wn + ni * 16 + l15) * 32 + quad * 8]);
#pragma unroll
            for (int mi = 0; mi < MI; ++mi)
#pragma unroll
                for (int ni = 0; ni < 4; ++ni)
                    acc[mi][ni] = __builtin_amdgcn_mfma_f32_16x16x32_bf16(
                        af[mi], bfv[ni], acc[mi][ni], 0, 0, 0);
        }
    }

    if (VT && n0 >= 2048) {
        // transposed in-place V write: 16 x 8B stores per thread
#pragma unroll
        for (int mi = 0; mi < MI; ++mi)
#pragma unroll
            for (int ni = 0; ni < 4; ++ni) {
                int col = n0 + wn + ni * 16 + l15;       // 2048..3071
                int r0  = m0 + wm + mi * 16 + quad * 4;  // s index, 4-aligned
                int bb  = r0 >> 11, s = r0 & 2047;
                size_t drow = (size_t)bb * 2048 + 2 * (col - 2048) + (s >> 10);
                unsigned short* dp = (unsigned short*)Cout + drow * QKV_N + 2048 + (s & 1023);
                *(ushort4*)dp = make_ushort4(f2b(acc[mi][ni][0]), f2b(acc[mi][ni][1]),
                                             f2b(acc[mi][ni][2]), f2b(acc[mi][ni][3]));
            }
        return;
    }

#pragma unroll
    for (int mi = 0; mi < MI; ++mi)
#pragma unroll
        for (int ni = 0; ni < 4; ++ni)
#pragma unroll
            for (int r = 0; r < 4; ++r) {
                int row = m0 + wm + mi * 16 + quad * 4 + r;
                int col = n0 + wn + ni * 16 + l15;
                float val = acc[mi][ni][r];
                if (OUT_BF16)
                    ((unsigned short*)Cout)[(size_t)row * N + col] = f2b(val);
                else
                    ((float*)Cout)[(size_t)row * N + col] = val;
            }
}

// Fused QKV: [4096,1024] x [3072,1024]^T -> [4096,3072] bf16.  768 blocks;
// (256,3) -> 3 blocks/CU so the whole grid co-resides.
// XCD-chunked bijective swizzle (768 % 8 == 0): each XCD gets a contiguous
// 96-block chunk -> contiguous m-range per XCD-L2 -> better A-panel reuse.
// V third written transposed in place (see gemm_bt_body).
__global__ __launch_bounds__(256, 3) void gemm_qkv(const unsigned short* __restrict__ xb,
                                                   const unsigned short* __restrict__ wqkv,
                                                   unsigned short* __restrict__ qkv) {
    int id = blockIdx.x + 24 * blockIdx.y;       // 0..767
    int sw = (id & 7) * 96 + (id >> 3);          // bijective, 96 blocks/XCD
    int n0 = (sw % 24) * 128;
    int m0 = (sw / 24) * 128;
    gemm_bt_body<128, true, true>(xb, wqkv, qkv, m0, n0, QKV_N, E_);
}

// Out-proj: TM=64, 512 blocks -> 2/CU.  Same XCD-chunked bijective swizzle
// (512 % 8 == 0): each XCD gets 64 consecutive sw ids = an m-contiguous
// 512-row span x all n -> A-panel 1MB + B 2MB fits the 4MB per-XCD L2.
__global__ __launch_bounds__(256, 2) void gemm_out(const unsigned short* __restrict__ a,
                                                   const unsigned short* __restrict__ wob,
                                                   float* __restrict__ c) {
    int id = blockIdx.x + 8 * blockIdx.y;        // 0..511
    int sw = (id & 7) * 64 + (id >> 3);          // bijective, 64 blocks/XCD
    gemm_bt_body<64, false, false>(a, wob, c, (sw >> 3) * 64, (sw & 7) * 128, E_, E_);
}

// ---------------- MFMA causal flash attention v18 ----------------
// = v13 (round-4 config, best measured total 165.7us: reg-staged K/V with T14
// issue-early prefetch, 128-kv outer tiles double-buffered, (c,31-c) pairing
// with dual-pattern balance remap, setprio around MFMA, native exp2) with ONE
// delta: row-sums via ones-MFMA (Lacc) instead of the lsum VALU chain +
// epilogue shuffle reduction.  v14-v17's staging/schedule restructurings all
// measured neutral-to-negative (42.7-47.4 vs v13's <=41.7): the kernel sits
// at a joint LDS-throughput x TLP optimum at 16 waves/CU + 16 rows/wave, so
// v13's shape is kept verbatim.  Lacc is the one mechanically-strict
// improvement isolated from v14 (VALUBusy 41 -> 27 measured, work moved to
// the 14%-busy MFMA pipe; denominator sums the same bf16-rounded P as the
// numerator, so ratio error cancels to first order).
__global__ __launch_bounds__(512, 4) void attn_kernel(const unsigned short* __restrict__ QKV,
                                                      unsigned short* __restrict__ O) {
    __shared__ unsigned short Ks[2][64 * 64];   // [sub][kv][d]  swizzled
    __shared__ unsigned short Vs[2][64 * 64];   // [sub][d][kv]  swizzled
    __shared__ unsigned short Ps[8][16 * 64];   // per wave [q][kv] swizzled

    const int b = blockIdx.z, h = blockIdx.y;
    const int cx = blockIdx.x;
    const int c0 = (cx & 1) ? (15 - (cx >> 1)) : (cx >> 1);
    const int c = (b == 0) ? c0 : (15 - c0);    // pair id 0..15, balance-remapped
    const int tid = threadIdx.x;
    const int w = tid >> 6, lane = tid & 63;
    const int quad = lane >> 4, l15 = lane & 15;
    const int lx = l15 & 7;
    // wave-group mapping: w<4 -> heavy chunk 31-c, w>=4 -> light chunk c
    const int chunk = (w < 4) ? (31 - c) : c;
    const int Q0 = chunk * 64 + (w & 3) * 16;   // wave's 16 q rows

    // Q B-frags (pre-scaled by C2_ via wq)
    const size_t qo = (size_t)(b * S_ + Q0 + l15) * QKV_N + h * D_;
    short8_t bq0 = *(const short8_t*)(QKV + qo + quad * 8);
    short8_t bq1 = *(const short8_t*)(QKV + qo + 32 + quad * 8);

    f32x4 Oacc[4] = {};
    f32x4 Lacc = {};
    const int qg = Q0 + l15;
    short8_t ones;
#pragma unroll
    for (int i = 0; i < 8; ++i) ones[i] = (short)0x3F80;   // bf16 1.0

    const int fo0 = ((quad) ^ lx) * 8;
    const int fo1 = ((4 + quad) ^ lx) * 8;
    const int krow = l15 * 64;
    int pwo[4];
#pragma unroll
    for (int tm = 0; tm < 4; ++tm)
        pwo[tm] = ((tm * 2 + (quad >> 1)) ^ lx) * 8 + (quad & 1) * 4;

    // staging: 512 threads, per sub-tile 1x16B K + 1x16B V each.
    const int srow = tid >> 3;
    const int scb  = tid & 7;
    const int swz  = (scb ^ (srow & 7)) * 8;
    const unsigned short* Kbase = QKV + (size_t)(b * S_) * QKV_N + 1024 + h * D_;
    // V third of qkv, transposed in place: row' = b*2048 + 2*(h*64+d) + (s>>10),
    // col' = 2048 + (s&1023).  This thread stages d = srow.
    const unsigned short* Vb2 = QKV + (size_t)(b * S_ + 2 * (h * D_ + srow)) * QKV_N + 2048;

    const int ntiles = 32 - c;                  // 64-kv tiles heavy chunk needs
    const int nT = (ntiles + 1) >> 1;           // 128-kv outer tiles

    // prologue: prefetch outer tile 0 into registers
    ushort8_t ka = *(const ushort8_t*)(Kbase + (size_t)srow * QKV_N + scb * 8);
    ushort8_t kb = *(const ushort8_t*)(Kbase + (size_t)(64 + srow) * QKV_N + scb * 8);
    ushort8_t va = *(const ushort8_t*)(Vb2 + scb * 8);
    ushort8_t vb = *(const ushort8_t*)(Vb2 + 64 + scb * 8);

    for (int t = 0; t < nT; ++t) {
        const int kt0 = t * 128;
        __syncthreads();   // previous outer tile's consumers done
        *(ushort8_t*)(&Ks[0][srow * 64 + swz]) = ka;
        *(ushort8_t*)(&Ks[1][srow * 64 + swz]) = kb;
        *(ushort8_t*)(&Vs[0][srow * 64 + swz]) = va;
        *(ushort8_t*)(&Vs[1][srow * 64 + swz]) = vb;
        __syncthreads();

        // T14: issue next outer tile's loads now; HBM latency hides under
        // this tile's compute phase.
        if (t + 1 < nT) {
            const int kn = kt0 + 128;
            ka = *(const ushort8_t*)(Kbase + (size_t)(kn + srow) * QKV_N + scb * 8);
            kb = *(const ushort8_t*)(Kbase + (size_t)(kn + 64 + srow) * QKV_N + scb * 8);
            va = *(const ushort8_t*)(Vb2 + (size_t)(kn >> 10) * QKV_N
                                         + (kn & 1023) + scb * 8);
            vb = *(const ushort8_t*)(Vb2 + (size_t)((kn + 64) >> 10) * QKV_N
                                         + ((kn + 64) & 1023) + scb * 8);
        }

#pragma unroll
        for (int s = 0; s < 2; ++s) {
            const int kt = kt0 + s * 64;
            if (kt > Q0 + 15) continue;         // beyond this wave's causal range
            const bool h2 = (kt + 32 <= Q0 + 15);

            if (kt + 63 <= Q0) {
                // ---- full tile: no mask ----
#pragma unroll
                for (int tm = 0; tm < 4; ++tm) {
                    short8_t ak0 = *(const short8_t*)(&Ks[s][tm * 1024 + krow + fo0]);
                    short8_t ak1 = *(const short8_t*)(&Ks[s][tm * 1024 + krow + fo1]);
                    f32x4 st = {0.f, 0.f, 0.f, 0.f};
                    __builtin_amdgcn_s_setprio(1);
                    st = __builtin_amdgcn_mfma_f32_16x16x32_bf16(ak0, bq0, st, 0, 0, 0);
                    st = __builtin_amdgcn_mfma_f32_16x16x32_bf16(ak1, bq1, st, 0, 0, 0);
                    __builtin_amdgcn_s_setprio(0);
                    float p0 = __builtin_amdgcn_exp2f(st[0]);
                    float p1 = __builtin_amdgcn_exp2f(st[1]);
                    float p2 = __builtin_amdgcn_exp2f(st[2]);
                    float p3 = __builtin_amdgcn_exp2f(st[3]);
                    ushort2 a = pkbf(p0, p1), c2 = pkbf(p2, p3);
                    *(ushort4*)(&Ps[w][krow + pwo[tm]]) = make_ushort4(a.x, a.y, c2.x, c2.y);
                }
            } else {
                // ---- diagonal-area: mask kv > q; zero dead-but-read blocks ----
                const int need = h2 ? 4 : 2;
                for (int tm = 0; tm < need; ++tm) {
                    if (kt + tm * 16 <= Q0 + 15) {
                        short8_t ak0 = *(const short8_t*)(&Ks[s][tm * 1024 + krow + fo0]);
                        short8_t ak1 = *(const short8_t*)(&Ks[s][tm * 1024 + krow + fo1]);
                        f32x4 st = {0.f, 0.f, 0.f, 0.f};
                        __builtin_amdgcn_s_setprio(1);
                        st = __builtin_amdgcn_mfma_f32_16x16x32_bf16(ak0, bq0, st, 0, 0, 0);
                        st = __builtin_amdgcn_mfma_f32_16x16x32_bf16(ak1, bq1, st, 0, 0, 0);
                        __builtin_amdgcn_s_setprio(0);
                        const int kvb = kt + tm * 16 + quad * 4;
                        float p0 = (kvb     > qg) ? 0.f : __builtin_amdgcn_exp2f(st[0]);
                        float p1 = (kvb + 1 > qg) ? 0.f : __builtin_amdgcn_exp2f(st[1]);
                        float p2 = (kvb + 2 > qg) ? 0.f : __builtin_amdgcn_exp2f(st[2]);
                        float p3 = (kvb + 3 > qg) ? 0.f : __builtin_amdgcn_exp2f(st[3]);
                        ushort2 a = pkbf(p0, p1), c2 = pkbf(p2, p3);
                        *(ushort4*)(&Ps[w][krow + pwo[tm]]) = make_ushort4(a.x, a.y, c2.x, c2.y);
                    } else {
                        *(ushort4*)(&Ps[w][krow + pwo[tm]]) = make_ushort4(0, 0, 0, 0);
                    }
                }
            }

            // ---- O += P V ;  Lacc += P * ones (row-sums) ----
#pragma unroll
            for (int kh = 0; kh < 2; ++kh) {
                if (kh == 1 && !h2) break;
                const int fo = kh ? fo1 : fo0;
                short8_t bv[4];
#pragma unroll
                for (int tn = 0; tn < 4; ++tn)
                    bv[tn] = *(const short8_t*)(&Vs[s][tn * 1024 + krow + fo]);
                short8_t ap = *(const short8_t*)(&Ps[w][krow + fo]);
                __builtin_amdgcn_s_setprio(1);
#pragma unroll
                for (int tn = 0; tn < 4; ++tn)
                    Oacc[tn] = __builtin_amdgcn_mfma_f32_16x16x32_bf16(
                        ap, bv[tn], Oacc[tn], 0, 0, 0);
                Lacc = __builtin_amdgcn_mfma_f32_16x16x32_bf16(ap, ones, Lacc, 0, 0, 0);
                __builtin_amdgcn_s_setprio(0);
            }
        }
    }

    // ---- epilogue: normalize, store bf16.  Lacc[r] = rowsum(q = quad*4+r),
    // uniform across l15 -- same row indexing as Oacc, no shuffles needed.
    float lir[4];
#pragma unroll
    for (int r = 0; r < 4; ++r)
        lir[r] = 1.f / Lacc[r];
#pragma unroll
    for (int tn = 0; tn < 4; ++tn)
#pragma unroll
        for (int r = 0; r < 4; ++r) {
            int row = Q0 + quad * 4 + r;
            O[(size_t)(b * S_ + row) * E_ + h * D_ + tn * 16 + l15] =
                f2b(Oacc[tn][r] * lir[r]);
        }
}

// ---------------- launch ----------------
extern "C" void kernel_launch(void* const* d_in, const int* in_sizes, int n_in,
                              void* d_out, int out_size, void* d_ws, size_t ws_size,
                              hipStream_t stream) {
    const float* x  = (const float*)d_in[0];
    const float* wq = (const float*)d_in[1];
    const float* wk = (const float*)d_in[2];
    const float* wv = (const float*)d_in[3];
    const float* wo = (const float*)d_in[4];
    float* out = (float*)d_out;

    unsigned short* ws   = (unsigned short*)d_ws;
    unsigned short* xb   = ws;                   // [0, 4194304)
    unsigned short* wqkv = ws + 4194304;         // 3 x 1048576 (wq|wk|wv)
    unsigned short* wob  = ws + 7340032;         // 1048576
    unsigned short* qkvb = ws + 8388608;         // 4096 x 3072 = 12582912
    unsigned short* ab   = ws + 20971520;        // 4194304

    cast_all<<<8192, 256, 0, stream>>>(x, wq, wk, wv, wo, xb, wqkv);
    gemm_qkv<<<dim3(24, 32), 256, 0, stream>>>(xb, wqkv, qkvb);
    attn_kernel<<<dim3(16, 16, 2), 512, 0, stream>>>(qkvb, ab);
    gemm_out<<<dim3(8, 64), 256, 0, stream>>>(ab, wob, out);
}